// Round 9
// baseline (268.918 us; speedup 1.0000x reference)
//
#include <hip/hip_runtime.h>

// GQA_22436909154699: softmax over a size-1 axis == 1.0, so the reference
// reduces to  out[bl, g*512+h*64+d] = (x @ Wkv + bkv)[bl, g*128+64+d].
// => one (16384 x 2048) @ (2048 x 256) GEMM (v-cols only) + broadcast x8.
// R16 = R13 with ONE variable changed: 256 -> 512 threads (8 waves = 2 per
// SIMD). Evidence: R12-R15 all run 1 wave/SIMD (4 waves, 1 blk/CU) and all
// pin at 2.0-2.3 TB/s with every pipe <8% busy -- no SIMD-level latency
// hiding; every lgkm/vmcnt/barrier gap idles the SIMD. m201's verified
// counted-vmcnt template runs 2 waves/SIMD for exactly this reason. Same
// 64x256 block tile, same 4-deep BK=32 DMA ring (96 KB), same swizzles
// byte-for-byte, same 64 phases, same read->stage->MFMA order. Wave =
// 32m x 64n (acc[2][4]); staging = 3 DMAs/wave/slab (1 A + 2 B); steady
// wait vmcnt(6) (9 outstanding -> 6), never drained in-loop.

#define EMBED 2048
#define SV 272  // epilogue LDS row stride in floats

typedef _Float16 half8 __attribute__((ext_vector_type(8)));
typedef _Float16 half4v __attribute__((ext_vector_type(4)));
typedef float f32x4 __attribute__((ext_vector_type(4)));

#define GLOAD16(g, l)                                                      \
  __builtin_amdgcn_global_load_lds(                                        \
      (const __attribute__((address_space(1))) void*)(g),                  \
      (__attribute__((address_space(3))) void*)(l), 16, 0, 0)

// ---- pre-pass: Bt[n][k] (f16) = Wkv[k][vcol(n)], vcol(n)=(n>>6)*128+64+(n&63)
__global__ __launch_bounds__(256) void prep_b(const float* __restrict__ Wkv,
                                              _Float16* __restrict__ Bt) {
  const int t = threadIdx.x;
  const int kb = blockIdx.x * 4;  // 512 blocks cover k = 0..2047
  const int vcol = ((t >> 6) * 128) + 64 + (t & 63);
  float v[4];
#pragma unroll
  for (int i = 0; i < 4; ++i) v[i] = Wkv[(size_t)(kb + i) * 512 + vcol];
  half4v h;
#pragma unroll
  for (int i = 0; i < 4; ++i) h[i] = (_Float16)v[i];
  *(half4v*)&Bt[(size_t)t * EMBED + kb] = h;
}

// ---- main: 256 blocks x 512 threads; block = 64 rows x 256 cols;
// 8 waves as 2m x 4n (wave tile 32m x 64n).
__global__ __launch_bounds__(512, 2) void gqa_main(
    const float* __restrict__ x, const _Float16* __restrict__ Bt,
    const float* __restrict__ bkv, float* __restrict__ out) {
  // ring: 4 x (A slab 64rows x 128B f32 = 8KB) + 4 x (B slab 256rows x 64B
  // f16 = 16KB) = 96 KB -> 1 block/CU, 8 waves = 2/SIMD.
  __shared__ __align__(16) char smem[4 * 8192 + 4 * 16384];
  char* const Ab = smem;
  char* const Bb = smem + 4 * 8192;
  float* const Vs = (float*)smem;  // epilogue overlay [8][SV] = 8.7 KB

  const int tid = threadIdx.x;
  const int v = tid >> 6;    // wave 0..7
  const int lane = tid & 63;
  const int lm = lane & 15;
  const int lq = lane >> 4;
  const int wm = v & 1;      // m-half (32 rows)
  const int wn = v >> 1;     // n-quarter (64 cols)
  const int row0 = blockIdx.x * 64;

  // ---- A staging (8 KB/slab = 512 thr x 16 B, 1 instr/thread):
  // wave v, lane: row = row0 + v*8 + (lane>>3), dest slot (lane&7)*16 within
  // the 128-B LDS row; src col = slot ^ ((row&7)<<4), row&7 = lane>>3.
  // dest offset = v*1024 + lane*16 (wave-uniform base + lane*16, verified).
  const int acol = ((lane & 7) ^ (lane >> 3)) << 4;
  const char* asrc = (const char*)x +
      (size_t)(row0 + v * 8 + (lane >> 3)) * (EMBED * 4) + acol;
  const int adst = v * 1024;
  // ---- B staging (16 KB/slab, 2 instr/thread): instr j: row n = j*128 +
  // v*16 + (lane>>2), dest slot (lane&3)*16 within the 64-B LDS row;
  // src col = slot ^ (((n>>1)&3)<<4), (n>>1)&3 = (lane>>3)&3.
  // dest offset = j*8192 + v*1024 + lane*16 (wave-uniform + lane*16).
  const int bcol = (((lane & 3) ^ ((lane >> 3) & 3)) << 4);
  const char* bsrc = (const char*)Bt +
      (size_t)(v * 16 + (lane >> 2)) * (EMBED * 2) + bcol;
  const int bdst = v * 1024;

  // 3 DMAs per slab per wave: 1 A + 2 B.
#define STAGE(b, s)                                                        \
  {                                                                        \
    GLOAD16(asrc + (size_t)(s) * 128, Ab + (b) * 8192 + adst);             \
    const char* bs_ = bsrc + (size_t)(s) * 64;                             \
    GLOAD16(bs_, Bb + (b) * 16384 + bdst);                                 \
    GLOAD16(bs_ + (size_t)128 * EMBED * 2,                                 \
            Bb + (b) * 16384 + 8192 + bdst);                               \
  }

  // read swizzles (lane-const), identical to R13
  const int arswz = (lm & 7) << 4;
  const int brswz = ((lm >> 1) & 3) << 4;
  const char* ard = Ab + (wm * 32 + lm) * 128;
  const char* brd = Bb + (wn * 64 + lm) * 64 + ((lq << 4) ^ brswz);

#define LOADFRAG(BC)                                                       \
  {                                                                        \
    _Pragma("unroll") for (int ni = 0; ni < 4; ++ni)                       \
        bfr_[ni] = *(const half8*)(brd + (BC) * 16384 + ni * 1024);        \
    _Pragma("unroll") for (int mi = 0; mi < 2; ++mi) {                     \
      a0r_[mi] =                                                           \
          *(const f32x4*)(ard + (BC) * 8192 + mi * 2048 + ((lq << 5) ^ arswz)); \
      a1r_[mi] = *(const f32x4*)(ard + (BC) * 8192 + mi * 2048 +           \
                                 (((lq << 5) + 16) ^ arswz));              \
    }                                                                      \
  }
#define MFMAFRAG()                                                         \
  _Pragma("unroll") for (int mi = 0; mi < 2; ++mi) {                       \
    half8 af_;                                                             \
    _Pragma("unroll") for (int j = 0; j < 4; ++j)                          \
        af_[j] = (_Float16)a0r_[mi][j];                                    \
    _Pragma("unroll") for (int j = 0; j < 4; ++j)                          \
        af_[4 + j] = (_Float16)a1r_[mi][j];                                \
    _Pragma("unroll") for (int ni = 0; ni < 4; ++ni)                       \
        acc[mi][ni] = __builtin_amdgcn_mfma_f32_16x16x32_f16(              \
            af_, bfr_[ni], acc[mi][ni], 0, 0, 0);                          \
  }

  f32x4 acc[2][4] = {};

  // prologue: stage slabs 0..2 (9 DMAs in flight per wave)
  STAGE(0, 0);
  STAGE(1, 1);
  STAGE(2, 2);

  // per slab t: vmcnt(6) [slab t's 3 DMAs retired] -> barrier [all waves'
  // slab-t data visible] -> ds_read frags -> STAGE(t+3 into buf (t+3)&3 =
  // slab t-1's, consumed before the barrier) -> cvt+MFMA.
  // Tail: junk re-stages of slab 63 keep vmcnt counts uniform.
  for (int tt = 0; tt < 64; tt += 4) {
#define ITER(T, BC, BS)                                                    \
    {                                                                      \
      asm volatile("s_waitcnt vmcnt(6)" ::: "memory");                     \
      __builtin_amdgcn_s_barrier();                                        \
      f32x4 a0r_[2], a1r_[2];                                              \
      half8 bfr_[4];                                                       \
      LOADFRAG(BC);                                                        \
      {                                                                    \
        const int ss_ = (T) + 3 < 64 ? (T) + 3 : 63;                       \
        STAGE(BS, ss_);                                                    \
      }                                                                    \
      MFMAFRAG();                                                          \
    }
    ITER(tt + 0, 0, 3)
    ITER(tt + 1, 1, 0)
    ITER(tt + 2, 2, 1)
    ITER(tt + 3, 3, 2)
#undef ITER
  }

  // epilogue: drain junk DMAs before overlaying smem with Vs
  asm volatile("s_waitcnt vmcnt(0)" ::: "memory");
  __syncthreads();

  float bias[4];
#pragma unroll
  for (int ni = 0; ni < 4; ++ni) bias[ni] = bkv[wn * 128 + 64 + ni * 16 + lm];

  // 8 chunks of 8 rows. acc row = wm*32 + mi*16 + lq*4 + r, so chunk
  // c = wm*4 + mi*2 + (lq>>1): writers are waves with wm==c>>2, lanes with
  // lq>>1==c&1, element mi=(c>>1)&1 (compile-time after unroll).
#pragma unroll
  for (int c = 0; c < 8; ++c) {
    const int mi = (c >> 1) & 1;
    if (wm == (c >> 2) && (lq >> 1) == (c & 1)) {
#pragma unroll
      for (int ni = 0; ni < 4; ++ni) {
        const int n = wn * 64 + ni * 16 + lm;
        f32x4 vv = acc[mi][ni];
#pragma unroll
        for (int r = 0; r < 4; ++r)
          Vs[((lq & 1) * 4 + r) * SV + n] = vv[r] + bias[ni];
      }
    }
    __syncthreads();
    f32x4* out4 = (f32x4*)(out + (size_t)(row0 + c * 8) * EMBED);
#pragma unroll
    for (int i = 0; i < 8; ++i) {
      const int f = i * 512 + tid;  // 8 rows x 512 float4
      const int row = f >> 9;
      const int c4 = f & 511;
      const int grp = c4 >> 7;
      const int d4 = c4 & 15;
      out4[(size_t)row * 512 + c4] =
          *(const f32x4*)&Vs[row * SV + grp * 64 + d4 * 4];
    }
    __syncthreads();
  }
}

extern "C" void kernel_launch(void* const* d_in, const int* in_sizes, int n_in,
                              void* d_out, int out_size, void* d_ws, size_t ws_size,
                              hipStream_t stream) {
  const float* x = (const float*)d_in[0];
  // d_in[1] = Wq, d_in[2] = bq : dead code (softmax over size-1 axis == 1)
  const float* Wkv = (const float*)d_in[3];
  const float* bkv = (const float*)d_in[4];
  float* out = (float*)d_out;
  _Float16* Bt = (_Float16*)d_ws;  // 256*2048 f16 = 1 MB scratch

  prep_b<<<512, 256, 0, stream>>>(Wkv, Bt);
  gqa_main<<<256, 512, 0, stream>>>(x, Bt, bkv, out);
}